// Round 3
// baseline (449.454 us; speedup 1.0000x reference)
//
#include <hip/hip_runtime.h>
#include <cstdint>

// Problem constants (fixed by the reference file).
#define Bn 64
#define Cn 256
#define Hn 56
#define Wn 56
#define HM 52            // H - (BS-1)
#define WM 52
#define BS 5
#define NPLANES (Bn * Cn)          // 16384
#define PLANE (Hn * Wn)            // 3136
#define ROW_I4 13                  // 52 ints = 13 int4 per mask row
#define PLANE_I4 (HM * ROW_I4)     // 676 int4 per mask plane
#define COUNTM ((long long)NPLANES * PLANE)  // 51380224

// Dilate geometry: 4 planes per block -> 4096 blocks.
// R2 post-mortem: 1 plane/block paid the fixed cost (LDS zero, 2 barriers,
// 56/256-active tail) against only 10.8 KB of loads. 4 planes gives 10
// unconditional load iterations and a 224/256-active tail.
#define PPB 4
#define DIL_BLOCKS (NPLANES / PPB)            // 4096
#define DIL_I4 (PPB * PLANE_I4)               // 2704 = 10*256 + 144

// Apply geometry: 8 float4 per thread, exact cover -> deeper MLP.
#define N4 ((int)(COUNTM / 4))                // 12,845,056
#define APPLY_PER_THREAD 8
#define APPLY_THREADS (N4 / APPLY_PER_THREAD) // 1,605,632
#define APPLY_BLOCKS (APPLY_THREADS / 256)    // 6,272

// ---------------------------------------------------------------------------
// Pass 1: 4 (b,c) planes per block. Load mask as int4, build per-row bitmasks
// via sparse LDS atomicOr (~8% of lanes fire at gamma=0.02), vertical OR
// window + horizontal shift-OR, write packed uint64 rows, fold popcount into
// the tail and block-reduce -> one plain store per block. No global atomics
// (same-address atomicAdds serialize at ~13 ns each).
// ---------------------------------------------------------------------------
__global__ __launch_bounds__(256) void dilate_kernel(
    const int4* __restrict__ mask4,
    uint64_t* __restrict__ dil,
    int* __restrict__ partial)
{
    __shared__ unsigned long long hrow[PPB * HM];   // 208 * 8 B = 1.7 KB
    __shared__ int wsum[4];

    const int tid    = threadIdx.x;
    const int plane0 = blockIdx.x * PPB;

    if (tid < PPB * HM) hrow[tid] = 0ull;
    __syncthreads();

    const int4* mbase = mask4 + (size_t)plane0 * PLANE_I4;

    // 2704 int4 = 10 full iterations + 144-lane remainder.
    #pragma unroll
    for (int k = 0; k < 11; ++k) {
        const int i = tid + k * 256;
        if (k < 10 || i < DIL_I4) {
            const int4 m = mbase[i];
            const unsigned nib = (m.x != 0 ? 1u : 0u) | (m.y != 0 ? 2u : 0u) |
                                 (m.z != 0 ? 4u : 0u) | (m.w != 0 ? 8u : 0u);
            if (nib) {                      // ~92% skipped at gamma=0.02
                const int p   = i / PLANE_I4;
                const int rem = i - p * PLANE_I4;
                const int row = rem / ROW_I4;
                const int c4  = (rem - row * ROW_I4) * 4;
                atomicOr(&hrow[p * HM + row], (unsigned long long)nib << c4);
            }
        }
    }
    __syncthreads();

    int pc = 0;
    if (tid < PPB * Hn) {                   // 224 active threads
        const int p = tid / Hn;
        const int r = tid - p * Hn;
        // vertical OR window over raw rows [r-4, r] clamped to [0,51]
        int lo = r - (BS - 1); if (lo < 0) lo = 0;
        int hi = r;            if (hi > HM - 1) hi = HM - 1;
        unsigned long long acc = 0ull;
        for (int q = lo; q <= hi; ++q) acc |= hrow[p * HM + q];
        // horizontal dilation (commutes with vertical OR); bits land in 0..55
        acc = acc | (acc << 1) | (acc << 2) | (acc << 3) | (acc << 4);
        dil[(size_t)(plane0 + p) * Hn + r] = acc;
        pc = __popcll(acc);
    }

    // Block popcount reduce across the 4 waves -> one plain store.
    #pragma unroll
    for (int off = 32; off > 0; off >>= 1)
        pc += __shfl_down(pc, off, 64);
    if ((tid & 63) == 0) wsum[tid >> 6] = pc;
    __syncthreads();
    if (tid == 0)
        partial[blockIdx.x] = wsum[0] + wsum[1] + wsum[2] + wsum[3];
}

// ---------------------------------------------------------------------------
// Pass 1.5: single-block reduce of 4096 partials (16 KB, L2-hot) -> the
// final f32 scale, computed exactly as the reference: (float)COUNTM/(float)ones.
// Launch-overhead-dominated (~4 µs).
// ---------------------------------------------------------------------------
__global__ __launch_bounds__(256) void reduce_kernel(
    const int* __restrict__ partial,
    float* __restrict__ scale_out)
{
    __shared__ int wsum[4];
    int t = 0;
    #pragma unroll
    for (int k = 0; k < DIL_BLOCKS / 256; ++k)     // 16 coalesced iterations
        t += partial[threadIdx.x + k * 256];

    #pragma unroll
    for (int off = 32; off > 0; off >>= 1)
        t += __shfl_down(t, off, 64);
    if ((threadIdx.x & 63) == 0) wsum[threadIdx.x >> 6] = t;
    __syncthreads();
    if (threadIdx.x == 0) {
        const long long dropped = wsum[0] + wsum[1] + wsum[2] + wsum[3];
        const long long ones = COUNTM - dropped;
        *scale_out = (float)COUNTM / (float)ones;
    }
}

// ---------------------------------------------------------------------------
// Pass 2: float4 streaming apply. 8 float4 per thread, fully unrolled ->
// 8 independent {dil, x4} load chains per thread (deep MLP), 6272 blocks
// keeps full TLP. dil reads are 14-lane-broadcast, L1/L2-hot.
// ---------------------------------------------------------------------------
__global__ __launch_bounds__(256) void apply_kernel(
    const float4* __restrict__ x4,
    const uint64_t* __restrict__ dil,
    const float* __restrict__ scale_in,
    float4* __restrict__ out4)
{
    const float scale = *scale_in;                 // scalar, L2-broadcast
    const int gtid = blockIdx.x * 256 + threadIdx.x;

    #pragma unroll
    for (int k = 0; k < APPLY_PER_THREAD; ++k) {
        const int i = gtid + k * APPLY_THREADS;    // coalesced across lanes
        const int plane = i / (PLANE / 4);         // 784 float4 per plane
        const int r4    = i - plane * (PLANE / 4);
        const int h     = r4 / (Wn / 4);           // 14 float4 per row
        const int w0    = (r4 - h * (Wn / 4)) * 4; // in {0,4,...,52}

        const uint64_t row = dil[plane * Hn + h];
        const unsigned bits = (unsigned)(row >> w0) & 0xFu;

        const float4 v = x4[i];
        float4 o;
        o.x = (bits & 1u) ? 0.0f : v.x * scale;
        o.y = (bits & 2u) ? 0.0f : v.y * scale;
        o.z = (bits & 4u) ? 0.0f : v.z * scale;
        o.w = (bits & 8u) ? 0.0f : v.w * scale;
        out4[i] = o;
    }
}

extern "C" void kernel_launch(void* const* d_in, const int* in_sizes, int n_in,
                              void* d_out, int out_size, void* d_ws, size_t ws_size,
                              hipStream_t stream)
{
    const float4* x4    = (const float4*)d_in[0];
    const int4*   mask4 = (const int4*)d_in[1];
    // d_in[2] = block_size (scalar 5) — fixed by the reference, hardcoded.

    uint64_t* dil     = (uint64_t*)d_ws;                          // 7,340,032 B
    int*      partial = (int*)((char*)d_ws + (size_t)NPLANES * Hn * 8);
    float*    scale   = (float*)((char*)d_ws + (size_t)NPLANES * Hn * 8
                                             + (size_t)DIL_BLOCKS * 4);

    // Every ws word used is written before it is read (dil, partial, scale),
    // so the 0xAA re-poison needs no memset — zero extra dispatches.
    dilate_kernel<<<DIL_BLOCKS, 256, 0, stream>>>(mask4, dil, partial);
    reduce_kernel<<<1, 256, 0, stream>>>(partial, scale);
    apply_kernel<<<APPLY_BLOCKS, 256, 0, stream>>>(x4, dil, scale, (float4*)d_out);
}

// Round 6
// 426.244 us; speedup vs baseline: 1.0545x; 1.0545x over previous
//
#include <hip/hip_runtime.h>
#include <cstdint>

// Problem constants (fixed by the reference file).
#define Bn 64
#define Cn 256
#define Hn 56
#define Wn 56
#define HM 52            // H - (BS-1)
#define WM 52
#define BS 5
#define NPLANES (Bn * Cn)          // 16384
#define PLANE (Hn * Wn)            // 3136
#define ROW_I4 13                  // 52 ints = 13 int4 per mask row
#define PLANE_I4 (HM * ROW_I4)     // 676 int4 per mask plane
#define COUNTM ((long long)NPLANES * PLANE)  // 51380224

// clang-native vector types: __builtin_nontemporal_* rejects HIP_vector_type
// (R4 compile failure) but accepts ext_vector_type. Same 16B layout/codegen.
typedef int   i32x4 __attribute__((ext_vector_type(4)));
typedef float f32x4 __attribute__((ext_vector_type(4)));

// Dilate geometry: 4 planes per block -> 4096 blocks, 4096 partials.
#define PPB 4
#define DIL_BLOCKS (NPLANES / PPB)            // 4096
#define DIL_I4 (PPB * PLANE_I4)               // 2704 = 10*256 + 144

// Apply geometry: 4 float4 per thread (R2-verified; 8/thr regressed in R3).
#define N4 ((int)(COUNTM / 4))                // 12,845,056
#define APPLY_PER_THREAD 4
#define APPLY_THREADS (N4 / APPLY_PER_THREAD) // 3,211,264
#define APPLY_BLOCKS (APPLY_THREADS / 256)    // 12,544

// ---------------------------------------------------------------------------
// Pass 1: 4 (b,c) planes per block. Nontemporal int4 mask loads (pure stream,
// keep L2/L3 for dil), sparse LDS atomicOr row bitmasks, vertical OR window +
// horizontal shift-OR, write packed uint64 rows, fold popcount into the tail,
// block-reduce -> ONE plain store per block (no global atomics: same-address
// atomicAdds serialize at ~13 ns each).
// ---------------------------------------------------------------------------
__global__ __launch_bounds__(256) void dilate_kernel(
    const i32x4* __restrict__ mask4,
    uint64_t* __restrict__ dil,
    int* __restrict__ partial)
{
    __shared__ unsigned long long hrow[PPB * HM];   // 208 * 8 B = 1.7 KB
    __shared__ int wsum[4];

    const int tid    = threadIdx.x;
    const int plane0 = blockIdx.x * PPB;

    if (tid < PPB * HM) hrow[tid] = 0ull;
    __syncthreads();

    const i32x4* mbase = mask4 + (size_t)plane0 * PLANE_I4;

    // 2704 int4 = 10 full iterations + 144-lane remainder.
    #pragma unroll
    for (int k = 0; k < 11; ++k) {
        const int i = tid + k * 256;
        if (k < 10 || i < DIL_I4) {
            const i32x4 m = __builtin_nontemporal_load(&mbase[i]);
            const unsigned nib = (m.x != 0 ? 1u : 0u) | (m.y != 0 ? 2u : 0u) |
                                 (m.z != 0 ? 4u : 0u) | (m.w != 0 ? 8u : 0u);
            if (nib) {                      // ~92% skipped at gamma=0.02
                const int p   = i / PLANE_I4;
                const int rem = i - p * PLANE_I4;
                const int row = rem / ROW_I4;
                const int c4  = (rem - row * ROW_I4) * 4;
                atomicOr(&hrow[p * HM + row], (unsigned long long)nib << c4);
            }
        }
    }
    __syncthreads();

    int pc = 0;
    if (tid < PPB * Hn) {                   // 224 active threads
        const int p = tid / Hn;
        const int r = tid - p * Hn;
        // vertical OR window over raw rows [r-4, r] clamped to [0,51]
        int lo = r - (BS - 1); if (lo < 0) lo = 0;
        int hi = r;            if (hi > HM - 1) hi = HM - 1;
        unsigned long long acc = 0ull;
        for (int q = lo; q <= hi; ++q) acc |= hrow[p * HM + q];
        // horizontal dilation (commutes with vertical OR); bits land in 0..55
        acc = acc | (acc << 1) | (acc << 2) | (acc << 3) | (acc << 4);
        dil[(size_t)(plane0 + p) * Hn + r] = acc;
        pc = __popcll(acc);
    }

    // Block popcount reduce across the 4 waves -> one plain store.
    #pragma unroll
    for (int off = 32; off > 0; off >>= 1)
        pc += __shfl_down(pc, off, 64);
    if ((tid & 63) == 0) wsum[tid >> 6] = pc;
    __syncthreads();
    if (tid == 0)
        partial[blockIdx.x] = wsum[0] + wsum[1] + wsum[2] + wsum[3];
}

// ---------------------------------------------------------------------------
// Pass 2: apply, with the scale reduce folded in (deletes the reduce kernel
// + one dispatch gap). Every block sums the 4096 partials (16 coalesced L2
// loads/thread, ~16 KB/block, identical integer sum -> identical f32 scale
// in every block, exact reference arithmetic). Then 4 independent
// {dil, x4} load chains per thread; nontemporal on the x/out streams keeps
// the 7.3 MB dil table cache-resident.
// ---------------------------------------------------------------------------
__global__ __launch_bounds__(256) void apply_kernel(
    const f32x4* __restrict__ x4,
    const uint64_t* __restrict__ dil,
    const int* __restrict__ partial,
    f32x4* __restrict__ out4)
{
    __shared__ int wsum[4];
    __shared__ float s_scale;

    const int tid = threadIdx.x;

    // --- per-block scale reduce (L2-hot, overlaps with x4 streaming) ---
    int t = 0;
    #pragma unroll
    for (int k = 0; k < DIL_BLOCKS / 256; ++k)     // 16 coalesced iterations
        t += partial[tid + k * 256];
    #pragma unroll
    for (int off = 32; off > 0; off >>= 1)
        t += __shfl_down(t, off, 64);
    if ((tid & 63) == 0) wsum[tid >> 6] = t;
    __syncthreads();
    if (tid == 0) {
        const long long dropped = wsum[0] + wsum[1] + wsum[2] + wsum[3];
        const long long ones = COUNTM - dropped;
        s_scale = (float)COUNTM / (float)ones;     // f32 divide, matches ref
    }
    __syncthreads();
    const float scale = s_scale;

    // --- streaming apply ---
    const int gtid = blockIdx.x * 256 + tid;
    #pragma unroll
    for (int k = 0; k < APPLY_PER_THREAD; ++k) {
        const int i = gtid + k * APPLY_THREADS;    // coalesced across lanes
        const int plane = i / (PLANE / 4);         // 784 float4 per plane
        const int r4    = i - plane * (PLANE / 4);
        const int h     = r4 / (Wn / 4);           // 14 float4 per row
        const int w0    = (r4 - h * (Wn / 4)) * 4; // in {0,4,...,52}

        const uint64_t row = dil[plane * Hn + h];
        const unsigned bits = (unsigned)(row >> w0) & 0xFu;

        const f32x4 v = __builtin_nontemporal_load(&x4[i]);
        f32x4 o;
        o.x = (bits & 1u) ? 0.0f : v.x * scale;
        o.y = (bits & 2u) ? 0.0f : v.y * scale;
        o.z = (bits & 4u) ? 0.0f : v.z * scale;
        o.w = (bits & 8u) ? 0.0f : v.w * scale;
        __builtin_nontemporal_store(o, &out4[i]);
    }
}

extern "C" void kernel_launch(void* const* d_in, const int* in_sizes, int n_in,
                              void* d_out, int out_size, void* d_ws, size_t ws_size,
                              hipStream_t stream)
{
    const f32x4* x4    = (const f32x4*)d_in[0];
    const i32x4* mask4 = (const i32x4*)d_in[1];
    // d_in[2] = block_size (scalar 5) — fixed by the reference, hardcoded.

    uint64_t* dil     = (uint64_t*)d_ws;                          // 7,340,032 B
    int*      partial = (int*)((char*)d_ws + (size_t)NPLANES * Hn * 8);

    // Every ws word used is written before it is read (dil, partial), so the
    // 0xAA re-poison needs no memset — zero extra dispatches.
    dilate_kernel<<<DIL_BLOCKS, 256, 0, stream>>>(mask4, dil, partial);
    apply_kernel<<<APPLY_BLOCKS, 256, 0, stream>>>(x4, dil, partial, (f32x4*)d_out);
}

// Round 7
// 423.147 us; speedup vs baseline: 1.0622x; 1.0073x over previous
//
#include <hip/hip_runtime.h>
#include <cstdint>

// Problem constants (fixed by the reference file).
#define Bn 64
#define Cn 256
#define Hn 56
#define Wn 56
#define HM 52            // H - (BS-1)
#define WM 52
#define BS 5
#define NPLANES (Bn * Cn)          // 16384
#define PLANE (Hn * Wn)            // 3136
#define ROW_I4 13                  // 52 ints = 13 int4 per mask row
#define PLANE_I4 (HM * ROW_I4)     // 676 int4 per mask plane
#define COUNTM ((long long)NPLANES * PLANE)  // 51380224

// clang-native vector types: __builtin_nontemporal_* rejects HIP_vector_type
// (R4 compile failure) but accepts ext_vector_type. Same 16B layout/codegen.
typedef int   i32x4 __attribute__((ext_vector_type(4)));
typedef float f32x4 __attribute__((ext_vector_type(4)));

// Dilate geometry: 8 planes per block -> 2048 blocks, 2048 partials.
// R6 (PPB=4) won ~17 µs vs PPB=1 chain; halve the per-block fixed cost again.
#define PPB 8
#define DIL_BLOCKS (NPLANES / PPB)            // 2048
#define DIL_I4 (PPB * PLANE_I4)               // 5408 = 21*256 + 32

// Apply geometry: 4 float4 per thread (R2/R6-verified; 8/thr regressed in R3).
#define N4 ((int)(COUNTM / 4))                // 12,845,056
#define APPLY_PER_THREAD 4
#define APPLY_THREADS (N4 / APPLY_PER_THREAD) // 3,211,264
#define APPLY_BLOCKS (APPLY_THREADS / 256)    // 12,544

// ---------------------------------------------------------------------------
// Pass 1: 8 (b,c) planes per block. Nontemporal int4 mask loads (pure stream,
// keep L2/L3 for dil), sparse LDS atomicOr row bitmasks, vertical OR window +
// horizontal shift-OR, write packed uint64 rows, fold popcount into the tail,
// block-reduce -> ONE plain store per block (no global atomics: same-address
// atomicAdds serialize at ~13 ns each).
// ---------------------------------------------------------------------------
__global__ __launch_bounds__(256) void dilate_kernel(
    const i32x4* __restrict__ mask4,
    uint64_t* __restrict__ dil,
    int* __restrict__ partial)
{
    __shared__ unsigned long long hrow[PPB * HM];   // 416 * 8 B = 3.3 KB
    __shared__ int wsum[4];

    const int tid    = threadIdx.x;
    const int plane0 = blockIdx.x * PPB;

    #pragma unroll
    for (int t = tid; t < PPB * HM; t += 256) hrow[t] = 0ull;
    __syncthreads();

    const i32x4* mbase = mask4 + (size_t)plane0 * PLANE_I4;

    // 5408 int4 = 21 full iterations + 32-lane remainder.
    #pragma unroll
    for (int k = 0; k < 22; ++k) {
        const int i = tid + k * 256;
        if (k < 21 || i < DIL_I4) {
            const i32x4 m = __builtin_nontemporal_load(&mbase[i]);
            const unsigned nib = (m.x != 0 ? 1u : 0u) | (m.y != 0 ? 2u : 0u) |
                                 (m.z != 0 ? 4u : 0u) | (m.w != 0 ? 8u : 0u);
            if (nib) {                      // ~92% skipped at gamma=0.02
                const int p   = i / PLANE_I4;
                const int rem = i - p * PLANE_I4;
                const int row = rem / ROW_I4;
                const int c4  = (rem - row * ROW_I4) * 4;
                atomicOr(&hrow[p * HM + row], (unsigned long long)nib << c4);
            }
        }
    }
    __syncthreads();

    int pc = 0;
    #pragma unroll
    for (int t = tid; t < PPB * Hn; t += 256) {     // 448 tail items, 2 iters
        const int p = t / Hn;
        const int r = t - p * Hn;
        // vertical OR window over raw rows [r-4, r] clamped to [0,51]
        int lo = r - (BS - 1); if (lo < 0) lo = 0;
        int hi = r;            if (hi > HM - 1) hi = HM - 1;
        unsigned long long acc = 0ull;
        for (int q = lo; q <= hi; ++q) acc |= hrow[p * HM + q];
        // horizontal dilation (commutes with vertical OR); bits land in 0..55
        acc = acc | (acc << 1) | (acc << 2) | (acc << 3) | (acc << 4);
        dil[(size_t)(plane0 + p) * Hn + r] = acc;
        pc += __popcll(acc);
    }

    // Block popcount reduce across the 4 waves -> one plain store.
    #pragma unroll
    for (int off = 32; off > 0; off >>= 1)
        pc += __shfl_down(pc, off, 64);
    if ((tid & 63) == 0) wsum[tid >> 6] = pc;
    __syncthreads();
    if (tid == 0)
        partial[blockIdx.x] = wsum[0] + wsum[1] + wsum[2] + wsum[3];
}

// ---------------------------------------------------------------------------
// Pass 2: apply, with the scale reduce folded in (no separate reduce
// dispatch). Every block sums the 2048 partials (8 coalesced L2 loads/thread,
// identical integer sum -> identical f32 scale in every block, exact
// reference arithmetic). Then 4 independent {dil, x4} load chains per thread;
// nontemporal on the x/out streams keeps the 7.3 MB dil table cache-resident.
// ---------------------------------------------------------------------------
__global__ __launch_bounds__(256) void apply_kernel(
    const f32x4* __restrict__ x4,
    const uint64_t* __restrict__ dil,
    const int* __restrict__ partial,
    f32x4* __restrict__ out4)
{
    __shared__ int wsum[4];
    __shared__ float s_scale;

    const int tid = threadIdx.x;

    // --- per-block scale reduce (L2-hot, overlaps with other blocks) ---
    int t = 0;
    #pragma unroll
    for (int k = 0; k < DIL_BLOCKS / 256; ++k)     // 8 coalesced iterations
        t += partial[tid + k * 256];
    #pragma unroll
    for (int off = 32; off > 0; off >>= 1)
        t += __shfl_down(t, off, 64);
    if ((tid & 63) == 0) wsum[tid >> 6] = t;
    __syncthreads();
    if (tid == 0) {
        const long long dropped = wsum[0] + wsum[1] + wsum[2] + wsum[3];
        const long long ones = COUNTM - dropped;
        s_scale = (float)COUNTM / (float)ones;     // f32 divide, matches ref
    }
    __syncthreads();
    const float scale = s_scale;

    // --- streaming apply ---
    const int gtid = blockIdx.x * 256 + tid;
    #pragma unroll
    for (int k = 0; k < APPLY_PER_THREAD; ++k) {
        const int i = gtid + k * APPLY_THREADS;    // coalesced across lanes
        const int plane = i / (PLANE / 4);         // 784 float4 per plane
        const int r4    = i - plane * (PLANE / 4);
        const int h     = r4 / (Wn / 4);           // 14 float4 per row
        const int w0    = (r4 - h * (Wn / 4)) * 4; // in {0,4,...,52}

        const uint64_t row = dil[plane * Hn + h];
        const unsigned bits = (unsigned)(row >> w0) & 0xFu;

        const f32x4 v = __builtin_nontemporal_load(&x4[i]);
        f32x4 o;
        o.x = (bits & 1u) ? 0.0f : v.x * scale;
        o.y = (bits & 2u) ? 0.0f : v.y * scale;
        o.z = (bits & 4u) ? 0.0f : v.z * scale;
        o.w = (bits & 8u) ? 0.0f : v.w * scale;
        __builtin_nontemporal_store(o, &out4[i]);
    }
}

extern "C" void kernel_launch(void* const* d_in, const int* in_sizes, int n_in,
                              void* d_out, int out_size, void* d_ws, size_t ws_size,
                              hipStream_t stream)
{
    const f32x4* x4    = (const f32x4*)d_in[0];
    const i32x4* mask4 = (const i32x4*)d_in[1];
    // d_in[2] = block_size (scalar 5) — fixed by the reference, hardcoded.

    uint64_t* dil     = (uint64_t*)d_ws;                          // 7,340,032 B
    int*      partial = (int*)((char*)d_ws + (size_t)NPLANES * Hn * 8);

    // Every ws word used is written before it is read (dil, partial), so the
    // 0xAA re-poison needs no memset — zero extra dispatches.
    dilate_kernel<<<DIL_BLOCKS, 256, 0, stream>>>(mask4, dil, partial);
    apply_kernel<<<APPLY_BLOCKS, 256, 0, stream>>>(x4, dil, partial, (f32x4*)d_out);
}